// Round 2
// baseline (322.538 us; speedup 1.0000x reference)
//
#include <hip/hip_runtime.h>

#define B_SZ 2
#define C_IN 384
#define N_TOK 2048
#define HEADS 8
#define DH 48
#define J3 1152          // 3 * INNER
#define QT 64
#define KT 64
#define ATTN_SCALE 0.14433756729740643f  // 48^-0.5

// ---------------- kernel 1: QKV projection + clip + scatter ----------------
// qkv[b,n,j] = sum_c x[b,c,n] * w_qkv[c,j]; j = which*384 + head*48 + d
__global__ __launch_bounds__(256) void qkv_kernel(
    const float* __restrict__ x, const float* __restrict__ w,
    float* __restrict__ Q, float* __restrict__ K, float* __restrict__ V) {
  __shared__ float As[32][64];   // [cc][mm]  (A is x[b][c][n]: naturally k-major)
  __shared__ float Bs[32][64];   // [cc][jj]
  const int tid = threadIdx.x;
  const int m0 = blockIdx.x * 64;     // m = b*2048 + n
  const int j0 = blockIdx.y * 64;
  const int b  = m0 >> 11;
  const int n0 = m0 & 2047;
  const int tx = tid & 15, ty = tid >> 4;
  const int mm0 = ty * 4, jj0 = tx * 4;
  float acc[4][4] = {};
  const float* xp = x + (size_t)b * C_IN * N_TOK + n0;
  for (int kk = 0; kk < C_IN; kk += 32) {
#pragma unroll
    for (int i = 0; i < 8; ++i) {
      int flat = tid + i * 256;
      int cc = flat >> 6, mm = flat & 63;
      As[cc][mm] = xp[(size_t)(kk + cc) * N_TOK + mm];
      Bs[cc][mm] = w[(size_t)(kk + cc) * J3 + j0 + mm];
    }
    __syncthreads();
#pragma unroll
    for (int cc = 0; cc < 32; ++cc) {
      const float4 a  = *(const float4*)&As[cc][mm0];
      const float4 bb = *(const float4*)&Bs[cc][jj0];
      const float av[4] = {a.x, a.y, a.z, a.w};
      const float bv[4] = {bb.x, bb.y, bb.z, bb.w};
#pragma unroll
      for (int i = 0; i < 4; ++i)
#pragma unroll
        for (int j = 0; j < 4; ++j) acc[i][j] += av[i] * bv[j];
    }
    __syncthreads();
  }
#pragma unroll
  for (int mi = 0; mi < 4; ++mi) {
    const int n = n0 + mm0 + mi;
#pragma unroll
    for (int ji = 0; ji < 4; ++ji) {
      const int j = j0 + jj0 + ji;
      const int which = j / 384;
      const int r = j - which * 384;
      const int head = r / DH;
      const int d = r - head * DH;
      const size_t off = ((size_t)(b * HEADS + head) * N_TOK + n) * DH + d;
      const float val = acc[mi][ji];
      if (which == 0)      Q[off] = fminf(fmaxf(val, -5.f), 5.f);
      else if (which == 1) K[off] = fminf(fmaxf(val, -5.f), 5.f);
      else                 V[off] = val;
    }
  }
}

// ---------------- kernel 2: flash attention (fp32, online softmax) ---------
// grid: (N_TOK/QT = 32, B*HEADS = 16), 256 threads.
__global__ __launch_bounds__(256) void attn_kernel(
    const float* __restrict__ Q, const float* __restrict__ K,
    const float* __restrict__ V, float* __restrict__ AO) {
  const int qt = blockIdx.x, bh = blockIdx.y;
  const int b = bh >> 3, h = bh & 7;
  const int n0 = qt * QT;
  const float* Qp = Q + ((size_t)bh * N_TOK + n0) * DH;
  const float* Kp = K + (size_t)bh * N_TOK * DH;
  const float* Vp = V + (size_t)bh * N_TOK * DH;

  __shared__ float Qs[DH][QT + 4];   // transposed, stride 68 (16B-aligned rows)
  __shared__ float Ks[DH][KT + 4];
  __shared__ float Vs[KT][DH];
  __shared__ float Ss[KT][QT];       // S then P, [kj][qi]
  __shared__ float mPart[4][QT];
  __shared__ float lPart[4][QT];
  __shared__ float mRow[QT];         // running max
  __shared__ float lRow[QT];         // running denom
  __shared__ float rsRow[QT];        // this-tile rescale factor

  const int tid = threadIdx.x;
  // Q tile load (transposed into LDS), fully coalesced global read
#pragma unroll
  for (int i = 0; i < (QT * DH) / 256; ++i) {
    int flat = tid + i * 256;
    int qi = flat / DH, d = flat - qi * DH;
    Qs[d][qi] = Qp[flat];
  }
  if (tid < QT) { mRow[tid] = -3.4e38f; lRow[tid] = 0.f; }

  // phase-3 / output mapping: thread owns 4 queries x 3 dims
  const int tx = tid & 15, ty = tid >> 4;
  const int qi0 = ty * 4, d0 = tx * 3;
  float Oacc[4][3];
#pragma unroll
  for (int i = 0; i < 4; ++i)
#pragma unroll
    for (int j = 0; j < 3; ++j) Oacc[i][j] = 0.f;

  // phase-1 mapping: tx -> qi block, ty -> kj block
  const int p1q = tx * 4;
  const int p1k = ty * 4;
  const int sqi = tid & 63, spart = tid >> 6;  // softmax mapping

  __syncthreads();

  for (int t0 = 0; t0 < N_TOK; t0 += KT) {
    // load K (transposed) + V (natural)
#pragma unroll
    for (int i = 0; i < (KT * DH) / 256; ++i) {
      int flat = tid + i * 256;
      int kj = flat / DH, d = flat - kj * DH;
      Ks[d][kj] = Kp[(size_t)t0 * DH + flat];
      Vs[kj][d] = Vp[(size_t)t0 * DH + flat];
    }
    __syncthreads();

    // phase 1: S[kj][qi] = scale * <Q[qi], K[kj]>
    {
      float acc[4][4] = {};
#pragma unroll
      for (int cc = 0; cc < DH; ++cc) {
        const float4 q4 = *(const float4*)&Qs[cc][p1q];
        const float4 k4 = *(const float4*)&Ks[cc][p1k];
        const float qv[4] = {q4.x, q4.y, q4.z, q4.w};
        const float kv[4] = {k4.x, k4.y, k4.z, k4.w};
#pragma unroll
        for (int i = 0; i < 4; ++i)
#pragma unroll
          for (int j = 0; j < 4; ++j) acc[i][j] += kv[i] * qv[j];
      }
#pragma unroll
      for (int i = 0; i < 4; ++i) {
        float4 s4;
        s4.x = acc[i][0] * ATTN_SCALE; s4.y = acc[i][1] * ATTN_SCALE;
        s4.z = acc[i][2] * ATTN_SCALE; s4.w = acc[i][3] * ATTN_SCALE;
        *(float4*)&Ss[p1k + i][p1q] = s4;
      }
    }
    __syncthreads();

    // phase 2a: per-query partial max over 16 keys each
    {
      float mx = -3.4e38f;
#pragma unroll
      for (int j = 0; j < 16; ++j) mx = fmaxf(mx, Ss[spart * 16 + j][sqi]);
      mPart[spart][sqi] = mx;
    }
    __syncthreads();
    if (tid < QT) {
      const float tm = fmaxf(fmaxf(mPart[0][tid], mPart[1][tid]),
                             fmaxf(mPart[2][tid], mPart[3][tid]));
      const float mo = mRow[tid];
      const float mn = fmaxf(mo, tm);
      const float rs = __expf(mo - mn);   // 0 on first tile
      mRow[tid] = mn;
      rsRow[tid] = rs;
      lRow[tid] *= rs;
    }
    __syncthreads();

    // phase 2b: P = exp(S - m), write back, partial row sums
    {
      const float mn = mRow[sqi];
      float s = 0.f;
#pragma unroll
      for (int j = 0; j < 16; ++j) {
        const float p = __expf(Ss[spart * 16 + j][sqi] - mn);
        Ss[spart * 16 + j][sqi] = p;
        s += p;
      }
      lPart[spart][sqi] = s;
    }
    __syncthreads();
    if (tid < QT) {
      lRow[tid] += lPart[0][tid] + lPart[1][tid] + lPart[2][tid] + lPart[3][tid];
    }

    // phase 3: O = O*rs + P @ V
    {
      float rs[4];
#pragma unroll
      for (int i = 0; i < 4; ++i) rs[i] = rsRow[qi0 + i];
#pragma unroll
      for (int i = 0; i < 4; ++i)
#pragma unroll
        for (int j = 0; j < 3; ++j) Oacc[i][j] *= rs[i];
      for (int kj = 0; kj < KT; ++kj) {
        const float4 p4 = *(const float4*)&Ss[kj][qi0];
        const float pv[4] = {p4.x, p4.y, p4.z, p4.w};
        const float v0 = Vs[kj][d0 + 0];
        const float v1 = Vs[kj][d0 + 1];
        const float v2 = Vs[kj][d0 + 2];
#pragma unroll
        for (int i = 0; i < 4; ++i) {
          Oacc[i][0] += pv[i] * v0;
          Oacc[i][1] += pv[i] * v1;
          Oacc[i][2] += pv[i] * v2;
        }
      }
    }
    __syncthreads();  // protect Ks/Vs/Ss/lRow before next tile
  }

  // epilogue: O /= l, store AO[b][n][h*48+d]
#pragma unroll
  for (int i = 0; i < 4; ++i) {
    const float inv = 1.f / lRow[qi0 + i];
    const size_t base = ((size_t)b * N_TOK + n0 + qi0 + i) * 384 + (size_t)h * DH + d0;
#pragma unroll
    for (int j = 0; j < 3; ++j) AO[base + j] = Oacc[i][j] * inv;
  }
}

// ---------------- kernel 3: out projection + bias + residual ---------------
// out[b,c,n] = x[b,c,n] + b_out[c] + sum_i AO[b,n,i] * w_out[i,c]
__global__ __launch_bounds__(256) void proj_kernel(
    const float* __restrict__ AO, const float* __restrict__ w_out,
    const float* __restrict__ b_out, const float* __restrict__ x,
    float* __restrict__ out) {
  __shared__ float As[32][68];   // [cc][mm], padded (write-transposed)
  __shared__ float Bs[32][64];   // [cc][jj]
  const int tid = threadIdx.x;
  const int m0 = blockIdx.x * 64;
  const int c0 = blockIdx.y * 64;
  const int b  = m0 >> 11;
  const int n0 = m0 & 2047;
  const int tx = tid & 15, ty = tid >> 4;
  const int mm0 = ty * 4, jj0 = tx * 4;
  float acc[4][4] = {};
  const float* ap = AO + (size_t)m0 * 384;
  for (int kk = 0; kk < 384; kk += 32) {
#pragma unroll
    for (int i = 0; i < 8; ++i) {
      int flat = tid + i * 256;
      int mm = flat >> 5, cc = flat & 31;
      As[cc][mm] = ap[(size_t)mm * 384 + kk + cc];
      int cc2 = flat >> 6, jj = flat & 63;
      Bs[cc2][jj] = w_out[(size_t)(kk + cc2) * 384 + c0 + jj];
    }
    __syncthreads();
#pragma unroll
    for (int cc = 0; cc < 32; ++cc) {
      const float4 a  = *(const float4*)&As[cc][mm0];
      const float4 bb = *(const float4*)&Bs[cc][jj0];
      const float av[4] = {a.x, a.y, a.z, a.w};
      const float bv[4] = {bb.x, bb.y, bb.z, bb.w};
#pragma unroll
      for (int i = 0; i < 4; ++i)
#pragma unroll
        for (int j = 0; j < 4; ++j) acc[i][j] += av[i] * bv[j];
    }
    __syncthreads();
  }
#pragma unroll
  for (int mi = 0; mi < 4; ++mi) {
    const int n = n0 + mm0 + mi;
#pragma unroll
    for (int ji = 0; ji < 4; ++ji) {
      const int c = c0 + jj0 + ji;
      const size_t off = ((size_t)b * 384 + c) * N_TOK + n;
      out[off] = x[off] + b_out[c] + acc[mi][ji];
    }
  }
}

// ---------------- launch ----------------
extern "C" void kernel_launch(void* const* d_in, const int* in_sizes, int n_in,
                              void* d_out, int out_size, void* d_ws, size_t ws_size,
                              hipStream_t stream) {
  const float* x     = (const float*)d_in[0];
  const float* w_qkv = (const float*)d_in[1];
  const float* w_out = (const float*)d_in[2];
  const float* b_out = (const float*)d_in[3];
  float* out = (float*)d_out;

  const size_t per = (size_t)B_SZ * HEADS * N_TOK * DH;  // 1,572,864 floats
  float* ws = (float*)d_ws;
  float* Q  = ws;
  float* K  = ws + per;
  float* V  = ws + 2 * per;
  float* AO = ws + 3 * per;  // [B][N][384], same element count

  qkv_kernel<<<dim3(64, 18), 256, 0, stream>>>(x, w_qkv, Q, K, V);
  attn_kernel<<<dim3(32, 16), 256, 0, stream>>>(Q, K, V, AO);
  proj_kernel<<<dim3(64, 6), 256, 0, stream>>>(AO, w_out, b_out, x, out);
}

// Round 5
// 140.155 us; speedup vs baseline: 2.3013x; 2.3013x over previous
//
#include <hip/hip_runtime.h>

#define B_SZ 2
#define C_IN 384
#define N_TOK 2048
#define HEADS 8
#define DH 48
#define J3 1152
#define ATTN_SCALE 0.14433756729740643f  // 48^-0.5

typedef __attribute__((ext_vector_type(8))) _Float16 f16x8;
typedef __attribute__((ext_vector_type(4))) _Float16 f16x4;
typedef __attribute__((ext_vector_type(4))) float f32x4;

__device__ __forceinline__ unsigned short f2h(float f) {
  _Float16 h = (_Float16)f;           // RTN convert
  return __builtin_bit_cast(unsigned short, h);
}

// ---------------- kernel 1: QKV projection + clip + scatter (fp16 out) -----
__global__ __launch_bounds__(256) void qkv_kernel(
    const float* __restrict__ x, const float* __restrict__ w,
    unsigned short* __restrict__ Qo, unsigned short* __restrict__ Ko,
    unsigned short* __restrict__ Vo) {
  __shared__ float As[32][64];
  __shared__ float Bs[32][64];
  const int tid = threadIdx.x;
  const int m0 = blockIdx.x * 64;
  const int j0 = blockIdx.y * 64;
  const int b  = m0 >> 11;
  const int n0 = m0 & 2047;
  const int tx = tid & 15, ty = tid >> 4;
  const int mm0 = ty * 4, jj0 = tx * 4;
  float acc[4][4] = {};
  const float* xp = x + (size_t)b * C_IN * N_TOK + n0;
  for (int kk = 0; kk < C_IN; kk += 32) {
#pragma unroll
    for (int i = 0; i < 8; ++i) {
      int flat = tid + i * 256;
      int cc = flat >> 6, mm = flat & 63;
      As[cc][mm] = xp[(size_t)(kk + cc) * N_TOK + mm];
      Bs[cc][mm] = w[(size_t)(kk + cc) * J3 + j0 + mm];
    }
    __syncthreads();
#pragma unroll
    for (int cc = 0; cc < 32; ++cc) {
      const float4 a  = *(const float4*)&As[cc][mm0];
      const float4 bb = *(const float4*)&Bs[cc][jj0];
      const float av[4] = {a.x, a.y, a.z, a.w};
      const float bv[4] = {bb.x, bb.y, bb.z, bb.w};
#pragma unroll
      for (int i = 0; i < 4; ++i)
#pragma unroll
        for (int j = 0; j < 4; ++j) acc[i][j] += av[i] * bv[j];
    }
    __syncthreads();
  }
#pragma unroll
  for (int mi = 0; mi < 4; ++mi) {
    const int n = n0 + mm0 + mi;
#pragma unroll
    for (int ji = 0; ji < 4; ++ji) {
      const int j = j0 + jj0 + ji;
      const int which = j / 384;
      const int r = j - which * 384;
      const int head = r / DH;
      const int d = r - head * DH;
      const int bh = b * HEADS + head;
      float val = acc[mi][ji];
      if (which == 0) {
        val = fminf(fmaxf(val, -5.f), 5.f) * ATTN_SCALE;
        Qo[((size_t)bh * N_TOK + n) * DH + d] = f2h(val);
      } else if (which == 1) {
        val = fminf(fmaxf(val, -5.f), 5.f);
        Ko[((size_t)bh * N_TOK + n) * DH + d] = f2h(val);
      } else {
        Vo[((size_t)bh * DH + d) * N_TOK + n] = f2h(val);  // V transposed
      }
    }
  }
}

// ---------------- kernel 2: flash attention, fp16 MFMA ---------------------
// grid (32, 16), 256 thr = 4 waves. Wave w owns q-cols n0+16w..+15.
// S^T = K·Q^T (scale pre-folded into Q); O^T = V^T·P^T.
// D-layout: col = lane&15, row = 4*(lane>>4)+reg.
__global__ __launch_bounds__(256) void attn_kernel(
    const unsigned short* __restrict__ Q, const unsigned short* __restrict__ K,
    const unsigned short* __restrict__ Vt, float* __restrict__ AO) {
  const int qt = blockIdx.x, bh = blockIdx.y;
  const int b = bh >> 3, h = bh & 7;
  const int n0 = qt * 64;
  const int tid = threadIdx.x;
  const int w = tid >> 6, lane = tid & 63;
  const int lc = lane & 15, lg = lane >> 4;

  __shared__ __align__(16) unsigned short Ks[64][56];  // [key 0..63][d 0..47 +pad]
  __shared__ __align__(16) unsigned short Vs[48][68];  // [d 0..47][key 0..63 +pad]
  // NOTE: Vs key-dim must be >= 64 (was 56: rows overlapped by 8 elements ->
  // keys 56..63 read row d+1 data => constant ~0.136 absmax error).
  // 68 = 64+4 pad: stride 136 B (34 dwords) spreads the 16-lanes-per-lg
  // V-fragment reads across banks (64-stride would be a 16-way conflict).

  // persistent Q fragments: B-operand of S^T, q = n0+16w+lc
  const unsigned short* Qrow = Q + ((size_t)bh * N_TOK + n0 + 16 * w + lc) * DH;
  const f16x8 qf0 = *(const f16x8*)(Qrow + 8 * lg);          // d = 8lg..8lg+7
  f16x8 qf1 = {0, 0, 0, 0, 0, 0, 0, 0};                      // d = 32+4lg..+3
  {
    const f16x4 t = *(const f16x4*)(Qrow + 32 + 4 * lg);
    qf1[0] = t[0]; qf1[1] = t[1]; qf1[2] = t[2]; qf1[3] = t[3];
  }

  const unsigned short* Kg = K + (size_t)bh * N_TOK * DH;
  const uint* Vg32 = (const uint*)(Vt + (size_t)bh * DH * N_TOK);

  float m_run = -1e30f, l_run = 0.f;
  f32x4 oacc[3] = {{0,0,0,0},{0,0,0,0},{0,0,0,0}};

  for (int t0 = 0; t0 < N_TOK; t0 += 64) {
    // stage K[64][48] and V^T[48][64] tiles (dword-coalesced)
    const uint* Ksrc = (const uint*)(Kg + (size_t)t0 * DH);
#pragma unroll
    for (int i = 0; i < 6; ++i) {
      const int dw = tid + i * 256;
      const int key = dw / 24, c = dw - key * 24;
      *(uint*)&Ks[key][2 * c] = Ksrc[dw];
      const int d = dw >> 5, c2 = dw & 31;
      *(uint*)&Vs[d][2 * c2] = Vg32[(size_t)d * 1024 + (t0 >> 1) + c2];
    }
    __syncthreads();

    // S^T[key][q]: A = K rows, B = Q rows (shared k-slot convention)
    f32x4 sac[4];
#pragma unroll
    for (int it = 0; it < 4; ++it) {
      const int krow = 16 * it + lc;
      const f16x8 kf0 = *(const f16x8*)&Ks[krow][8 * lg];
      f16x8 kf1 = {0, 0, 0, 0, 0, 0, 0, 0};
      const f16x4 t = *(const f16x4*)&Ks[krow][32 + 4 * lg];
      kf1[0] = t[0]; kf1[1] = t[1]; kf1[2] = t[2]; kf1[3] = t[3];
      const f32x4 z = {0.f, 0.f, 0.f, 0.f};
      f32x4 s = __builtin_amdgcn_mfma_f32_16x16x32_f16(kf0, qf0, z, 0, 0, 0);
      sac[it]  = __builtin_amdgcn_mfma_f32_16x16x32_f16(kf1, qf1, s, 0, 0, 0);
    }

    // online softmax; lane's q = lc; its 16 keys are 16it+4lg+r
    float mt = -1e30f;
#pragma unroll
    for (int it = 0; it < 4; ++it)
#pragma unroll
      for (int r = 0; r < 4; ++r) mt = fmaxf(mt, sac[it][r]);
    mt = fmaxf(mt, __shfl_xor(mt, 16, 64));
    mt = fmaxf(mt, __shfl_xor(mt, 32, 64));
    const float mn = fmaxf(m_run, mt);
    const float rs = __expf(m_run - mn);
    m_run = mn;
    float p[4][4];
    float ps = 0.f;
#pragma unroll
    for (int it = 0; it < 4; ++it)
#pragma unroll
      for (int r = 0; r < 4; ++r) {
        p[it][r] = __expf(sac[it][r] - mn);
        ps += p[it][r];
      }
    ps += __shfl_xor(ps, 16, 64);
    ps += __shfl_xor(ps, 32, 64);
    l_run = l_run * rs + ps;
#pragma unroll
    for (int itd = 0; itd < 3; ++itd)
#pragma unroll
      for (int r = 0; r < 4; ++r) oacc[itd][r] *= rs;

    // pack P^T to fp16 B-fragments: slot (g,e) -> key 32ks+4g+(e&3)+16(e>>2)
    f16x8 pt[2];
#pragma unroll
    for (int ks = 0; ks < 2; ++ks) {
      pt[ks][0] = (_Float16)p[2 * ks][0];
      pt[ks][1] = (_Float16)p[2 * ks][1];
      pt[ks][2] = (_Float16)p[2 * ks][2];
      pt[ks][3] = (_Float16)p[2 * ks][3];
      pt[ks][4] = (_Float16)p[2 * ks + 1][0];
      pt[ks][5] = (_Float16)p[2 * ks + 1][1];
      pt[ks][6] = (_Float16)p[2 * ks + 1][2];
      pt[ks][7] = (_Float16)p[2 * ks + 1][3];
    }

    // O^T += V^T · P^T  (A-slot (g,e) reads the same key map)
#pragma unroll
    for (int itd = 0; itd < 3; ++itd) {
      const int drow = 16 * itd + lc;
#pragma unroll
      for (int ks = 0; ks < 2; ++ks) {
        const f16x4 v0 = *(const f16x4*)&Vs[drow][4 * lg + 32 * ks];
        const f16x4 v1 = *(const f16x4*)&Vs[drow][4 * lg + 32 * ks + 16];
        f16x8 vf;
        vf[0] = v0[0]; vf[1] = v0[1]; vf[2] = v0[2]; vf[3] = v0[3];
        vf[4] = v1[0]; vf[5] = v1[1]; vf[6] = v1[2]; vf[7] = v1[3];
        oacc[itd] = __builtin_amdgcn_mfma_f32_16x16x32_f16(vf, pt[ks], oacc[itd], 0, 0, 0);
      }
    }
    __syncthreads();
  }

  // epilogue: lane holds O^T[d = 16itd+4lg+r][q = lc]
  const float inv = 1.f / l_run;
#pragma unroll
  for (int itd = 0; itd < 3; ++itd)
#pragma unroll
    for (int r = 0; r < 4; ++r) {
      const int d = 16 * itd + 4 * lg + r;
      AO[((size_t)b * N_TOK + n0 + 16 * w + lc) * 384 + h * DH + d] =
          oacc[itd][r] * inv;
    }
}

// ---------------- kernel 3: out projection + bias + residual ---------------
__global__ __launch_bounds__(256) void proj_kernel(
    const float* __restrict__ AO, const float* __restrict__ w_out,
    const float* __restrict__ b_out, const float* __restrict__ x,
    float* __restrict__ out) {
  __shared__ float As[32][68];
  __shared__ float Bs[32][64];
  const int tid = threadIdx.x;
  const int m0 = blockIdx.x * 64;
  const int c0 = blockIdx.y * 64;
  const int b  = m0 >> 11;
  const int n0 = m0 & 2047;
  const int tx = tid & 15, ty = tid >> 4;
  const int mm0 = ty * 4, jj0 = tx * 4;
  float acc[4][4] = {};
  const float* ap = AO + (size_t)m0 * 384;
  for (int kk = 0; kk < 384; kk += 32) {
#pragma unroll
    for (int i = 0; i < 8; ++i) {
      int flat = tid + i * 256;
      int mm = flat >> 5, cc = flat & 31;
      As[cc][mm] = ap[(size_t)mm * 384 + kk + cc];
      int cc2 = flat >> 6, jj = flat & 63;
      Bs[cc2][jj] = w_out[(size_t)(kk + cc2) * 384 + c0 + jj];
    }
    __syncthreads();
#pragma unroll
    for (int cc = 0; cc < 32; ++cc) {
      const float4 a  = *(const float4*)&As[cc][mm0];
      const float4 bb = *(const float4*)&Bs[cc][jj0];
      const float av[4] = {a.x, a.y, a.z, a.w};
      const float bv[4] = {bb.x, bb.y, bb.z, bb.w};
#pragma unroll
      for (int i = 0; i < 4; ++i)
#pragma unroll
        for (int j = 0; j < 4; ++j) acc[i][j] += av[i] * bv[j];
    }
    __syncthreads();
  }
#pragma unroll
  for (int mi = 0; mi < 4; ++mi) {
    const int n = n0 + mm0 + mi;
#pragma unroll
    for (int ji = 0; ji < 4; ++ji) {
      const int c = c0 + jj0 + ji;
      const size_t off = ((size_t)b * 384 + c) * N_TOK + n;
      out[off] = x[off] + b_out[c] + acc[mi][ji];
    }
  }
}

// ---------------- launch ----------------
extern "C" void kernel_launch(void* const* d_in, const int* in_sizes, int n_in,
                              void* d_out, int out_size, void* d_ws, size_t ws_size,
                              hipStream_t stream) {
  const float* x     = (const float*)d_in[0];
  const float* w_qkv = (const float*)d_in[1];
  const float* w_out = (const float*)d_in[2];
  const float* b_out = (const float*)d_in[3];
  float* out = (float*)d_out;

  char* ws = (char*)d_ws;
  unsigned short* Qb = (unsigned short*)(ws);             // 16*2048*48*2 = 3 MB
  unsigned short* Kb = (unsigned short*)(ws + 3145728);
  unsigned short* Vb = (unsigned short*)(ws + 6291456);   // transposed [bh][d][n]
  float*          AO = (float*)(ws + 9437184);            // [B][N][384] fp32

  qkv_kernel<<<dim3(64, 18), 256, 0, stream>>>(x, w_qkv, Qb, Kb, Vb);
  attn_kernel<<<dim3(32, 16), 256, 0, stream>>>(Qb, Kb, Vb, AO);
  proj_kernel<<<dim3(64, 6), 256, 0, stream>>>(AO, w_out, b_out, x, out);
}

// Round 6
// 92.152 us; speedup vs baseline: 3.5001x; 1.5209x over previous
//
#include <hip/hip_runtime.h>

#define B_SZ 2
#define C_IN 384
#define N_TOK 2048
#define HEADS 8
#define DH 48
#define J3 1152
#define ATTN_SCALE 0.14433756729740643f  // 48^-0.5

typedef __attribute__((ext_vector_type(8))) _Float16 f16x8;
typedef __attribute__((ext_vector_type(4))) _Float16 f16x4;
typedef __attribute__((ext_vector_type(4))) float f32x4;

__device__ __forceinline__ unsigned short f2h(float f) {
  _Float16 h = (_Float16)f;
  return __builtin_bit_cast(unsigned short, h);
}

// ---------------- kernel 0: fused transpose+convert prep -------------------
// z=0/1: x[b][384][2048] -> xh[b][n][c] fp16 ; z=2: w_qkv[384][1152] -> wqh[j][c]
// z=3: w_out[384][384] -> woh[c_out][i].  dst[c][r] = (fp16)src[r][c].
__global__ __launch_bounds__(256) void tr_kernel(
    const float* __restrict__ x, const float* __restrict__ wq,
    const float* __restrict__ wo, unsigned short* __restrict__ xh,
    unsigned short* __restrict__ wqh, unsigned short* __restrict__ woh) {
  const int z = blockIdx.z;
  const float* src;
  unsigned short* dst;
  int C;  // src col count (R is always 384 here)
  if (z < 2) {
    src = x + (size_t)z * C_IN * N_TOK;
    dst = xh + (size_t)z * N_TOK * C_IN;
    C = N_TOK;
  } else if (z == 2) {
    src = wq; dst = wqh; C = J3;
  } else {
    src = wo; dst = woh; C = C_IN;
  }
  const int c0 = blockIdx.x * 64;
  const int r0 = blockIdx.y * 64;
  if (c0 >= C) return;
  __shared__ unsigned short T[64][74];
  const int tid = threadIdx.x;
  const int cc = tid & 63;
#pragma unroll
  for (int i = 0; i < 16; ++i) {
    const int rr = 4 * i + (tid >> 6);
    T[cc][rr] = f2h(src[(size_t)(r0 + rr) * C + c0 + cc]);
  }
  __syncthreads();
  const int cc2 = tid >> 2;
  const int seg = (tid & 3) * 16;
  uint v[8];
#pragma unroll
  for (int k = 0; k < 8; ++k)
    v[k] = (uint)T[cc2][seg + 2 * k] | ((uint)T[cc2][seg + 2 * k + 1] << 16);
  unsigned short* dp = dst + (size_t)(c0 + cc2) * C_IN + r0 + seg;
  *(uint4*)dp = make_uint4(v[0], v[1], v[2], v[3]);
  *(uint4*)(dp + 8) = make_uint4(v[4], v[5], v[6], v[7]);
}

// ---------------- kernel 1: QKV GEMM via fp16 MFMA -------------------------
// C[m][j] = sum_c xh[m][c] * wqh[j][c]; block = 128m x 64j, K-chunks of 64.
// A-frag: row = lane&15, k-slot (lg,e) -> k = 8lg+e (validated convention).
// D: row(m) = 4lg+reg, col(j) = lane&15.
__global__ __launch_bounds__(256) void qkv_mfma(
    const unsigned short* __restrict__ xh, const unsigned short* __restrict__ wqh,
    unsigned short* __restrict__ Qo, unsigned short* __restrict__ Ko,
    unsigned short* __restrict__ Vo) {
  __shared__ __align__(16) unsigned short Ts[128][72];
  __shared__ __align__(16) unsigned short Ws[64][72];
  const int tid = threadIdx.x;
  const int w = tid >> 6, lane = tid & 63;
  const int lc = lane & 15, lg = lane >> 4;
  const int m0 = blockIdx.x * 128;
  const int j0 = blockIdx.y * 64;
  const int b = m0 >> 11;

  f32x4 acc[2][4];
#pragma unroll
  for (int i = 0; i < 2; ++i)
#pragma unroll
    for (int j = 0; j < 4; ++j) acc[i][j] = (f32x4){0.f, 0.f, 0.f, 0.f};

  const int trow = tid & 127, tseg = tid >> 7;        // Ts staging map
  const int wrow = tid & 63,  wseg = tid >> 6;        // Ws staging map

  for (int kk = 0; kk < C_IN; kk += 64) {
    {
      const uint4* s = (const uint4*)(xh + (size_t)(m0 + trow) * C_IN + kk + tseg * 32);
      uint4* d = (uint4*)&Ts[trow][tseg * 32];
      d[0] = s[0]; d[1] = s[1]; d[2] = s[2]; d[3] = s[3];
      const uint4* s2 = (const uint4*)(wqh + (size_t)(j0 + wrow) * C_IN + kk + wseg * 16);
      uint4* d2 = (uint4*)&Ws[wrow][wseg * 16];
      d2[0] = s2[0]; d2[1] = s2[1];
    }
    __syncthreads();
    f16x8 a[2][2], bf[4][2];
#pragma unroll
    for (int mt = 0; mt < 2; ++mt)
#pragma unroll
      for (int kh = 0; kh < 2; ++kh)
        a[mt][kh] = *(const f16x8*)&Ts[32 * w + 16 * mt + lc][32 * kh + 8 * lg];
#pragma unroll
    for (int jt = 0; jt < 4; ++jt)
#pragma unroll
      for (int kh = 0; kh < 2; ++kh)
        bf[jt][kh] = *(const f16x8*)&Ws[16 * jt + lc][32 * kh + 8 * lg];
#pragma unroll
    for (int mt = 0; mt < 2; ++mt)
#pragma unroll
      for (int jt = 0; jt < 4; ++jt)
#pragma unroll
        for (int kh = 0; kh < 2; ++kh)
          acc[mt][jt] = __builtin_amdgcn_mfma_f32_16x16x32_f16(a[mt][kh], bf[jt][kh], acc[mt][jt], 0, 0, 0);
    __syncthreads();
  }

  // epilogue: j0 is 64-aligned and 384%64==0 -> which/head uniform per jt
#pragma unroll
  for (int jt = 0; jt < 4; ++jt) {
    const int jlo = j0 + 16 * jt;
    const int which = jlo / 384;
    const int rr = jlo - which * 384;
    const int head = rr / DH;
    const int dbase = rr - head * DH;     // in {0,16,32}
    const int d = dbase + lc;
    const int bh = b * HEADS + head;
#pragma unroll
    for (int mt = 0; mt < 2; ++mt)
#pragma unroll
      for (int r = 0; r < 4; ++r) {
        const int n = (m0 + 32 * w + 16 * mt + 4 * lg + r) & 2047;
        float val = acc[mt][jt][r];
        if (which == 0) {
          val = fminf(fmaxf(val, -5.f), 5.f) * ATTN_SCALE;
          Qo[((size_t)bh * N_TOK + n) * DH + d] = f2h(val);
        } else if (which == 1) {
          val = fminf(fmaxf(val, -5.f), 5.f);
          Ko[((size_t)bh * N_TOK + n) * DH + d] = f2h(val);
        } else {
          Vo[((size_t)bh * DH + d) * N_TOK + n] = f2h(val);
        }
      }
  }
}

// ---------------- kernel 2: flash attention, fp16 MFMA (AO -> fp16) --------
__global__ __launch_bounds__(256) void attn_kernel(
    const unsigned short* __restrict__ Q, const unsigned short* __restrict__ K,
    const unsigned short* __restrict__ Vt, unsigned short* __restrict__ AOh) {
  const int qt = blockIdx.x, bh = blockIdx.y;
  const int b = bh >> 3, h = bh & 7;
  const int n0 = qt * 64;
  const int tid = threadIdx.x;
  const int w = tid >> 6, lane = tid & 63;
  const int lc = lane & 15, lg = lane >> 4;

  __shared__ __align__(16) unsigned short Ks[64][56];
  __shared__ __align__(16) unsigned short Vs[48][68];  // key dim 64 + 4 pad

  const unsigned short* Qrow = Q + ((size_t)bh * N_TOK + n0 + 16 * w + lc) * DH;
  const f16x8 qf0 = *(const f16x8*)(Qrow + 8 * lg);
  f16x8 qf1 = {0, 0, 0, 0, 0, 0, 0, 0};
  {
    const f16x4 t = *(const f16x4*)(Qrow + 32 + 4 * lg);
    qf1[0] = t[0]; qf1[1] = t[1]; qf1[2] = t[2]; qf1[3] = t[3];
  }

  const unsigned short* Kg = K + (size_t)bh * N_TOK * DH;
  const uint* Vg32 = (const uint*)(Vt + (size_t)bh * DH * N_TOK);

  float m_run = -1e30f, l_run = 0.f;
  f32x4 oacc[3] = {{0,0,0,0},{0,0,0,0},{0,0,0,0}};

  for (int t0 = 0; t0 < N_TOK; t0 += 64) {
    const uint* Ksrc = (const uint*)(Kg + (size_t)t0 * DH);
#pragma unroll
    for (int i = 0; i < 6; ++i) {
      const int dw = tid + i * 256;
      const int key = dw / 24, c = dw - key * 24;
      *(uint*)&Ks[key][2 * c] = Ksrc[dw];
      const int d = dw >> 5, c2 = dw & 31;
      *(uint*)&Vs[d][2 * c2] = Vg32[(size_t)d * 1024 + (t0 >> 1) + c2];
    }
    __syncthreads();

    f32x4 sac[4];
#pragma unroll
    for (int it = 0; it < 4; ++it) {
      const int krow = 16 * it + lc;
      const f16x8 kf0 = *(const f16x8*)&Ks[krow][8 * lg];
      f16x8 kf1 = {0, 0, 0, 0, 0, 0, 0, 0};
      const f16x4 t = *(const f16x4*)&Ks[krow][32 + 4 * lg];
      kf1[0] = t[0]; kf1[1] = t[1]; kf1[2] = t[2]; kf1[3] = t[3];
      const f32x4 z = {0.f, 0.f, 0.f, 0.f};
      f32x4 s = __builtin_amdgcn_mfma_f32_16x16x32_f16(kf0, qf0, z, 0, 0, 0);
      sac[it]  = __builtin_amdgcn_mfma_f32_16x16x32_f16(kf1, qf1, s, 0, 0, 0);
    }

    float mt = -1e30f;
#pragma unroll
    for (int it = 0; it < 4; ++it)
#pragma unroll
      for (int r = 0; r < 4; ++r) mt = fmaxf(mt, sac[it][r]);
    mt = fmaxf(mt, __shfl_xor(mt, 16, 64));
    mt = fmaxf(mt, __shfl_xor(mt, 32, 64));
    const float mn = fmaxf(m_run, mt);
    const float rs = __expf(m_run - mn);
    m_run = mn;
    float p[4][4];
    float ps = 0.f;
#pragma unroll
    for (int it = 0; it < 4; ++it)
#pragma unroll
      for (int r = 0; r < 4; ++r) {
        p[it][r] = __expf(sac[it][r] - mn);
        ps += p[it][r];
      }
    ps += __shfl_xor(ps, 16, 64);
    ps += __shfl_xor(ps, 32, 64);
    l_run = l_run * rs + ps;
#pragma unroll
    for (int itd = 0; itd < 3; ++itd)
#pragma unroll
      for (int r = 0; r < 4; ++r) oacc[itd][r] *= rs;

    f16x8 pt[2];
#pragma unroll
    for (int ks = 0; ks < 2; ++ks) {
      pt[ks][0] = (_Float16)p[2 * ks][0];
      pt[ks][1] = (_Float16)p[2 * ks][1];
      pt[ks][2] = (_Float16)p[2 * ks][2];
      pt[ks][3] = (_Float16)p[2 * ks][3];
      pt[ks][4] = (_Float16)p[2 * ks + 1][0];
      pt[ks][5] = (_Float16)p[2 * ks + 1][1];
      pt[ks][6] = (_Float16)p[2 * ks + 1][2];
      pt[ks][7] = (_Float16)p[2 * ks + 1][3];
    }

#pragma unroll
    for (int itd = 0; itd < 3; ++itd) {
      const int drow = 16 * itd + lc;
#pragma unroll
      for (int ks = 0; ks < 2; ++ks) {
        const f16x4 v0 = *(const f16x4*)&Vs[drow][4 * lg + 32 * ks];
        const f16x4 v1 = *(const f16x4*)&Vs[drow][4 * lg + 32 * ks + 16];
        f16x8 vf;
        vf[0] = v0[0]; vf[1] = v0[1]; vf[2] = v0[2]; vf[3] = v0[3];
        vf[4] = v1[0]; vf[5] = v1[1]; vf[6] = v1[2]; vf[7] = v1[3];
        oacc[itd] = __builtin_amdgcn_mfma_f32_16x16x32_f16(vf, pt[ks], oacc[itd], 0, 0, 0);
      }
    }
    __syncthreads();
  }

  const float inv = 1.f / l_run;
  unsigned short* Ap = AOh + ((size_t)b * N_TOK + n0 + 16 * w + lc) * 384 + h * DH;
#pragma unroll
  for (int itd = 0; itd < 3; ++itd) {
    const int d = 16 * itd + 4 * lg;
    uint2 pk;
    pk.x = (uint)f2h(oacc[itd][0] * inv) | ((uint)f2h(oacc[itd][1] * inv) << 16);
    pk.y = (uint)f2h(oacc[itd][2] * inv) | ((uint)f2h(oacc[itd][3] * inv) << 16);
    *(uint2*)(Ap + d) = pk;
  }
}

// ---------------- kernel 3: out projection via fp16 MFMA (swapped) ---------
// D[c][m]: A = woh rows (c_out, k=i), B = AOh rows (m, k=i).
// Stores land n-contiguous per lg group.
__global__ __launch_bounds__(256) void proj_mfma(
    const unsigned short* __restrict__ AOh, const unsigned short* __restrict__ woh,
    const float* __restrict__ b_out, const float* __restrict__ x,
    float* __restrict__ out) {
  __shared__ __align__(16) unsigned short As[64][72];    // woh tile
  __shared__ __align__(16) unsigned short Bs[128][72];   // AO tile
  const int tid = threadIdx.x;
  const int w = tid >> 6, lane = tid & 63;
  const int lc = lane & 15, lg = lane >> 4;
  const int c0 = blockIdx.x * 64;
  const int m0 = blockIdx.y * 128;
  const int b = m0 >> 11;

  f32x4 acc[4][2];
#pragma unroll
  for (int i = 0; i < 4; ++i)
#pragma unroll
    for (int j = 0; j < 2; ++j) acc[i][j] = (f32x4){0.f, 0.f, 0.f, 0.f};

  const int arow = tid & 63,  aseg = tid >> 6;
  const int brow = tid & 127, bseg = tid >> 7;

  for (int kk = 0; kk < C_IN; kk += 64) {
    {
      const uint4* s = (const uint4*)(woh + (size_t)(c0 + arow) * C_IN + kk + aseg * 16);
      uint4* d = (uint4*)&As[arow][aseg * 16];
      d[0] = s[0]; d[1] = s[1];
      const uint4* s2 = (const uint4*)(AOh + (size_t)(m0 + brow) * C_IN + kk + bseg * 32);
      uint4* d2 = (uint4*)&Bs[brow][bseg * 32];
      d2[0] = s2[0]; d2[1] = s2[1]; d2[2] = s2[2]; d2[3] = s2[3];
    }
    __syncthreads();
    f16x8 a[4][2], bf[2][2];
#pragma unroll
    for (int ct = 0; ct < 4; ++ct)
#pragma unroll
      for (int kh = 0; kh < 2; ++kh)
        a[ct][kh] = *(const f16x8*)&As[16 * ct + lc][32 * kh + 8 * lg];
#pragma unroll
    for (int mt = 0; mt < 2; ++mt)
#pragma unroll
      for (int kh = 0; kh < 2; ++kh)
        bf[mt][kh] = *(const f16x8*)&Bs[32 * w + 16 * mt + lc][32 * kh + 8 * lg];
#pragma unroll
    for (int ct = 0; ct < 4; ++ct)
#pragma unroll
      for (int mt = 0; mt < 2; ++mt)
#pragma unroll
        for (int kh = 0; kh < 2; ++kh)
          acc[ct][mt] = __builtin_amdgcn_mfma_f32_16x16x32_f16(a[ct][kh], bf[mt][kh], acc[ct][mt], 0, 0, 0);
    __syncthreads();
  }

#pragma unroll
  for (int ct = 0; ct < 4; ++ct)
#pragma unroll
    for (int r = 0; r < 4; ++r) {
      const int c = c0 + 16 * ct + 4 * lg + r;
      const float bias = b_out[c];
#pragma unroll
      for (int mt = 0; mt < 2; ++mt) {
        const int n = (m0 + 32 * w + 16 * mt + lc) & 2047;
        const size_t off = ((size_t)b * C_IN + c) * N_TOK + n;
        out[off] = x[off] + bias + acc[ct][mt][r];
      }
    }
}

// ---------------- launch ----------------
extern "C" void kernel_launch(void* const* d_in, const int* in_sizes, int n_in,
                              void* d_out, int out_size, void* d_ws, size_t ws_size,
                              hipStream_t stream) {
  const float* x     = (const float*)d_in[0];
  const float* w_qkv = (const float*)d_in[1];
  const float* w_out = (const float*)d_in[2];
  const float* b_out = (const float*)d_in[3];
  float* out = (float*)d_out;

  char* ws = (char*)d_ws;
  unsigned short* xh  = (unsigned short*)(ws);             // 3,145,728 B
  unsigned short* wqh = (unsigned short*)(ws + 3145728);   //   884,736 B
  unsigned short* woh = (unsigned short*)(ws + 4030464);   //   294,912 B
  unsigned short* Qb  = (unsigned short*)(ws + 4325376);   // 3,145,728 B
  unsigned short* Kb  = (unsigned short*)(ws + 7471104);   // 3,145,728 B
  unsigned short* Vb  = (unsigned short*)(ws + 10616832);  // 3,145,728 B
  unsigned short* AOh = (unsigned short*)(ws + 13762560);  // 3,145,728 B

  tr_kernel<<<dim3(32, 6, 4), 256, 0, stream>>>(x, w_qkv, w_out, xh, wqh, woh);
  qkv_mfma<<<dim3(32, 18), 256, 0, stream>>>(xh, wqh, Qb, Kb, Vb);
  attn_kernel<<<dim3(32, 16), 256, 0, stream>>>(Qb, Kb, Vb, AOh);
  proj_mfma<<<dim3(6, 32), 256, 0, stream>>>(AOh, woh, b_out, x, out);
}

// Round 7
// 81.608 us; speedup vs baseline: 3.9523x; 1.1292x over previous
//
#include <hip/hip_runtime.h>

#define B_SZ 2
#define C_IN 384
#define N_TOK 2048
#define HEADS 8
#define DH 48
#define J3 1152
#define ATTN_SCALE 0.14433756729740643f  // 48^-0.5

typedef __attribute__((ext_vector_type(8))) _Float16 f16x8;
typedef __attribute__((ext_vector_type(4))) _Float16 f16x4;
typedef __attribute__((ext_vector_type(4))) float f32x4;

__device__ __forceinline__ unsigned short f2h(float f) {
  _Float16 h = (_Float16)f;
  return __builtin_bit_cast(unsigned short, h);
}
__device__ __forceinline__ uint pk2(float a, float b) {
  return __builtin_bit_cast(uint, __builtin_amdgcn_cvt_pkrtz(a, b));
}

// ---------------- kernel 0: fused transpose+convert prep -------------------
__global__ __launch_bounds__(256) void tr_kernel(
    const float* __restrict__ x, const float* __restrict__ wq,
    const float* __restrict__ wo, unsigned short* __restrict__ xh,
    unsigned short* __restrict__ wqh, unsigned short* __restrict__ woh) {
  const int z = blockIdx.z;
  const float* src;
  unsigned short* dst;
  int C;
  if (z < 2) {
    src = x + (size_t)z * C_IN * N_TOK;
    dst = xh + (size_t)z * N_TOK * C_IN;
    C = N_TOK;
  } else if (z == 2) {
    src = wq; dst = wqh; C = J3;
  } else {
    src = wo; dst = woh; C = C_IN;
  }
  const int c0 = blockIdx.x * 64;
  const int r0 = blockIdx.y * 64;
  if (c0 >= C) return;
  __shared__ unsigned short T[64][74];
  const int tid = threadIdx.x;
  const int cc = tid & 63;
#pragma unroll
  for (int i = 0; i < 16; ++i) {
    const int rr = 4 * i + (tid >> 6);
    T[cc][rr] = f2h(src[(size_t)(r0 + rr) * C + c0 + cc]);
  }
  __syncthreads();
  const int cc2 = tid >> 2;
  const int seg = (tid & 3) * 16;
  uint v[8];
#pragma unroll
  for (int k = 0; k < 8; ++k)
    v[k] = (uint)T[cc2][seg + 2 * k] | ((uint)T[cc2][seg + 2 * k + 1] << 16);
  unsigned short* dp = dst + (size_t)(c0 + cc2) * C_IN + r0 + seg;
  *(uint4*)dp = make_uint4(v[0], v[1], v[2], v[3]);
  *(uint4*)(dp + 8) = make_uint4(v[4], v[5], v[6], v[7]);
}

// ---------------- kernel 1: QKV GEMM via fp16 MFMA -------------------------
__global__ __launch_bounds__(256) void qkv_mfma(
    const unsigned short* __restrict__ xh, const unsigned short* __restrict__ wqh,
    unsigned short* __restrict__ Qo, unsigned short* __restrict__ Ko,
    unsigned short* __restrict__ Vo) {
  __shared__ __align__(16) unsigned short Ts[128][72];
  __shared__ __align__(16) unsigned short Ws[64][72];
  const int tid = threadIdx.x;
  const int w = tid >> 6, lane = tid & 63;
  const int lc = lane & 15, lg = lane >> 4;
  const int m0 = blockIdx.x * 128;
  const int j0 = blockIdx.y * 64;
  const int b = m0 >> 11;

  f32x4 acc[2][4];
#pragma unroll
  for (int i = 0; i < 2; ++i)
#pragma unroll
    for (int j = 0; j < 4; ++j) acc[i][j] = (f32x4){0.f, 0.f, 0.f, 0.f};

  const int trow = tid & 127, tseg = tid >> 7;
  const int wrow = tid & 63,  wseg = tid >> 6;

  for (int kk = 0; kk < C_IN; kk += 64) {
    {
      const uint4* s = (const uint4*)(xh + (size_t)(m0 + trow) * C_IN + kk + tseg * 32);
      uint4* d = (uint4*)&Ts[trow][tseg * 32];
      d[0] = s[0]; d[1] = s[1]; d[2] = s[2]; d[3] = s[3];
      const uint4* s2 = (const uint4*)(wqh + (size_t)(j0 + wrow) * C_IN + kk + wseg * 16);
      uint4* d2 = (uint4*)&Ws[wrow][wseg * 16];
      d2[0] = s2[0]; d2[1] = s2[1];
    }
    __syncthreads();
    f16x8 a[2][2], bf[4][2];
#pragma unroll
    for (int mt = 0; mt < 2; ++mt)
#pragma unroll
      for (int kh = 0; kh < 2; ++kh)
        a[mt][kh] = *(const f16x8*)&Ts[32 * w + 16 * mt + lc][32 * kh + 8 * lg];
#pragma unroll
    for (int jt = 0; jt < 4; ++jt)
#pragma unroll
      for (int kh = 0; kh < 2; ++kh)
        bf[jt][kh] = *(const f16x8*)&Ws[16 * jt + lc][32 * kh + 8 * lg];
#pragma unroll
    for (int mt = 0; mt < 2; ++mt)
#pragma unroll
      for (int jt = 0; jt < 4; ++jt)
#pragma unroll
        for (int kh = 0; kh < 2; ++kh)
          acc[mt][jt] = __builtin_amdgcn_mfma_f32_16x16x32_f16(a[mt][kh], bf[jt][kh], acc[mt][jt], 0, 0, 0);
    __syncthreads();
  }

#pragma unroll
  for (int jt = 0; jt < 4; ++jt) {
    const int jlo = j0 + 16 * jt;
    const int which = jlo / 384;
    const int rr = jlo - which * 384;
    const int head = rr / DH;
    const int dbase = rr - head * DH;
    const int d = dbase + lc;
    const int bh = b * HEADS + head;
#pragma unroll
    for (int mt = 0; mt < 2; ++mt)
#pragma unroll
      for (int r = 0; r < 4; ++r) {
        const int n = (m0 + 32 * w + 16 * mt + 4 * lg + r) & 2047;
        float val = acc[mt][jt][r];
        if (which == 0) {
          val = fminf(fmaxf(val, -5.f), 5.f) * ATTN_SCALE;
          Qo[((size_t)bh * N_TOK + n) * DH + d] = f2h(val);
        } else if (which == 1) {
          val = fminf(fmaxf(val, -5.f), 5.f);
          Ko[((size_t)bh * N_TOK + n) * DH + d] = f2h(val);
        } else {
          Vo[((size_t)bh * DH + d) * N_TOK + n] = f2h(val);
        }
      }
  }
}

// ---------------- kernel 2: flash attention, fp16 MFMA, K-split ------------
// grid (16 qt, 16 bh, 2 ks), 512 thr = 8 waves; wave w owns q = n0+16w+lc.
// Emits UNNORMALIZED O partial (fp16) + per-row (m,l).
__global__ __launch_bounds__(512) void attn_kernel(
    const unsigned short* __restrict__ Q, const unsigned short* __restrict__ K,
    const unsigned short* __restrict__ Vt, unsigned short* __restrict__ Opart,
    float2* __restrict__ ml) {
  const int qt = blockIdx.x, bh = blockIdx.y, ks = blockIdx.z;
  const int b = bh >> 3, h = bh & 7;
  const int n0 = qt * 128;
  const int tid = threadIdx.x;
  const int w = tid >> 6, lane = tid & 63;
  const int lc = lane & 15, lg = lane >> 4;

  __shared__ __align__(16) unsigned short Ks[64][56];  // [key][d 0..47 +pad]
  __shared__ __align__(16) unsigned short Vs[48][68];  // [d][key 0..63 +pad]

  const unsigned short* Qrow = Q + ((size_t)bh * N_TOK + n0 + 16 * w + lc) * DH;
  const f16x8 qf0 = *(const f16x8*)(Qrow + 8 * lg);
  f16x8 qf1 = {0, 0, 0, 0, 0, 0, 0, 0};
  {
    const f16x4 t = *(const f16x4*)(Qrow + 32 + 4 * lg);
    qf1[0] = t[0]; qf1[1] = t[1]; qf1[2] = t[2]; qf1[3] = t[3];
  }

  const unsigned short* Kg = K + (size_t)bh * N_TOK * DH + (size_t)ks * 1024 * DH;
  const uint* Vg32 = (const uint*)(Vt + (size_t)bh * DH * N_TOK) + ks * 512;

  float m_run = -1e30f, l_run = 0.f;
  f32x4 oacc[3] = {{0,0,0,0},{0,0,0,0},{0,0,0,0}};

  for (int t0 = 0; t0 < 1024; t0 += 64) {
    // stage K[64][48] + V^T[48][64]: 1536 dwords each, 512 threads x 3
    const uint* Ksrc = (const uint*)(Kg + (size_t)t0 * DH);
#pragma unroll
    for (int i = 0; i < 3; ++i) {
      const int dw = tid + i * 512;
      const int key = dw / 24, c = dw - key * 24;
      *(uint*)&Ks[key][2 * c] = Ksrc[dw];
      const int d = dw >> 5, c2 = dw & 31;
      *(uint*)&Vs[d][2 * c2] = Vg32[(size_t)d * 1024 + (t0 >> 1) + c2];
    }
    __syncthreads();

    f32x4 sac[4];
#pragma unroll
    for (int it = 0; it < 4; ++it) {
      const int krow = 16 * it + lc;
      const f16x8 kf0 = *(const f16x8*)&Ks[krow][8 * lg];
      f16x8 kf1 = {0, 0, 0, 0, 0, 0, 0, 0};
      const f16x4 t = *(const f16x4*)&Ks[krow][32 + 4 * lg];
      kf1[0] = t[0]; kf1[1] = t[1]; kf1[2] = t[2]; kf1[3] = t[3];
      const f32x4 z = {0.f, 0.f, 0.f, 0.f};
      f32x4 s = __builtin_amdgcn_mfma_f32_16x16x32_f16(kf0, qf0, z, 0, 0, 0);
      sac[it]  = __builtin_amdgcn_mfma_f32_16x16x32_f16(kf1, qf1, s, 0, 0, 0);
    }

    float mt = -1e30f;
#pragma unroll
    for (int it = 0; it < 4; ++it)
#pragma unroll
      for (int r = 0; r < 4; ++r) mt = fmaxf(mt, sac[it][r]);
    mt = fmaxf(mt, __shfl_xor(mt, 16, 64));
    mt = fmaxf(mt, __shfl_xor(mt, 32, 64));
    const float mn = fmaxf(m_run, mt);
    const float rs = __expf(m_run - mn);
    m_run = mn;
    float p[4][4];
    float ps = 0.f;
#pragma unroll
    for (int it = 0; it < 4; ++it)
#pragma unroll
      for (int r = 0; r < 4; ++r) {
        p[it][r] = __expf(sac[it][r] - mn);
        ps += p[it][r];
      }
    ps += __shfl_xor(ps, 16, 64);
    ps += __shfl_xor(ps, 32, 64);
    l_run = l_run * rs + ps;
#pragma unroll
    for (int itd = 0; itd < 3; ++itd)
#pragma unroll
      for (int r = 0; r < 4; ++r) oacc[itd][r] *= rs;

    // pack P^T via cvt_pkrtz: pt[ks2][0..3]=p[2ks2][0..3], [4..7]=p[2ks2+1]
    f16x8 pt[2];
#pragma unroll
    for (int ks2 = 0; ks2 < 2; ++ks2) {
      union { f16x8 v; uint u[4]; } pu;
      pu.u[0] = pk2(p[2 * ks2][0], p[2 * ks2][1]);
      pu.u[1] = pk2(p[2 * ks2][2], p[2 * ks2][3]);
      pu.u[2] = pk2(p[2 * ks2 + 1][0], p[2 * ks2 + 1][1]);
      pu.u[3] = pk2(p[2 * ks2 + 1][2], p[2 * ks2 + 1][3]);
      pt[ks2] = pu.v;
    }

#pragma unroll
    for (int itd = 0; itd < 3; ++itd) {
      const int drow = 16 * itd + lc;
#pragma unroll
      for (int ks2 = 0; ks2 < 2; ++ks2) {
        const f16x4 v0 = *(const f16x4*)&Vs[drow][4 * lg + 32 * ks2];
        const f16x4 v1 = *(const f16x4*)&Vs[drow][4 * lg + 32 * ks2 + 16];
        f16x8 vf;
        vf[0] = v0[0]; vf[1] = v0[1]; vf[2] = v0[2]; vf[3] = v0[3];
        vf[4] = v1[0]; vf[5] = v1[1]; vf[6] = v1[2]; vf[7] = v1[3];
        oacc[itd] = __builtin_amdgcn_mfma_f32_16x16x32_f16(vf, pt[ks2], oacc[itd], 0, 0, 0);
      }
    }
    __syncthreads();
  }

  // epilogue: unnormalized partial + (m,l)
  if (lg == 0)
    ml[(size_t)(ks * 16 + bh) * N_TOK + n0 + 16 * w + lc] = make_float2(m_run, l_run);
  unsigned short* Ap = Opart +
      ((size_t)(ks * B_SZ + b) * N_TOK + n0 + 16 * w + lc) * 384 + h * DH;
#pragma unroll
  for (int itd = 0; itd < 3; ++itd) {
    uint2 pkv;
    pkv.x = pk2(oacc[itd][0], oacc[itd][1]);
    pkv.y = pk2(oacc[itd][2], oacc[itd][3]);
    *(uint2*)(Ap + 16 * itd + 4 * lg) = pkv;
  }
}

// ---------------- kernel 2b: combine the 2 key-split partials --------------
__global__ __launch_bounds__(256) void combine_kernel(
    const unsigned short* __restrict__ Opart, const float2* __restrict__ ml,
    unsigned short* __restrict__ AOh) {
  const int vid = blockIdx.x * 256 + threadIdx.x;  // 196608 vec8's
  const int c8 = vid % 48;
  const int n  = (vid / 48) & 2047;
  const int b  = vid / (48 * 2048);
  const int c0 = c8 * 8;
  const int h  = c0 / 48;          // 48 % 8 == 0 -> uniform per vec8
  const int bh = b * 8 + h;
  const float2 ml1 = ml[(size_t)bh * N_TOK + n];
  const float2 ml2 = ml[(size_t)(16 + bh) * N_TOK + n];
  const float m = fmaxf(ml1.x, ml2.x);
  const float w1 = __expf(ml1.x - m), w2 = __expf(ml2.x - m);
  const float inv = 1.f / (ml1.y * w1 + ml2.y * w2);
  const float s1 = w1 * inv, s2 = w2 * inv;
  const size_t o1 = ((size_t)b * N_TOK + n) * 384 + c0;
  const size_t o2 = o1 + (size_t)B_SZ * N_TOK * 384;
  union { uint4 q; _Float16 e[8]; } u1, u2, r;
  u1.q = *(const uint4*)(Opart + o1);
  u2.q = *(const uint4*)(Opart + o2);
#pragma unroll
  for (int k = 0; k < 8; k += 2) {
    const float a = (float)u1.e[k] * s1 + (float)u2.e[k] * s2;
    const float bb = (float)u1.e[k + 1] * s1 + (float)u2.e[k + 1] * s2;
    *(uint*)&r.e[k] = pk2(a, bb);
  }
  *(uint4*)(AOh + o1) = r.q;
}

// ---------------- kernel 3: out projection via fp16 MFMA (swapped) ---------
__global__ __launch_bounds__(256) void proj_mfma(
    const unsigned short* __restrict__ AOh, const unsigned short* __restrict__ woh,
    const float* __restrict__ b_out, const float* __restrict__ x,
    float* __restrict__ out) {
  __shared__ __align__(16) unsigned short As[64][72];
  __shared__ __align__(16) unsigned short Bs[128][72];
  const int tid = threadIdx.x;
  const int w = tid >> 6, lane = tid & 63;
  const int lc = lane & 15, lg = lane >> 4;
  const int c0 = blockIdx.x * 64;
  const int m0 = blockIdx.y * 128;
  const int b = m0 >> 11;

  f32x4 acc[4][2];
#pragma unroll
  for (int i = 0; i < 4; ++i)
#pragma unroll
    for (int j = 0; j < 2; ++j) acc[i][j] = (f32x4){0.f, 0.f, 0.f, 0.f};

  const int arow = tid & 63,  aseg = tid >> 6;
  const int brow = tid & 127, bseg = tid >> 7;

  for (int kk = 0; kk < C_IN; kk += 64) {
    {
      const uint4* s = (const uint4*)(woh + (size_t)(c0 + arow) * C_IN + kk + aseg * 16);
      uint4* d = (uint4*)&As[arow][aseg * 16];
      d[0] = s[0]; d[1] = s[1];
      const uint4* s2 = (const uint4*)(AOh + (size_t)(m0 + brow) * C_IN + kk + bseg * 32);
      uint4* d2 = (uint4*)&Bs[brow][bseg * 32];
      d2[0] = s2[0]; d2[1] = s2[1]; d2[2] = s2[2]; d2[3] = s2[3];
    }
    __syncthreads();
    f16x8 a[4][2], bf[2][2];
#pragma unroll
    for (int ct = 0; ct < 4; ++ct)
#pragma unroll
      for (int kh = 0; kh < 2; ++kh)
        a[ct][kh] = *(const f16x8*)&As[16 * ct + lc][32 * kh + 8 * lg];
#pragma unroll
    for (int mt = 0; mt < 2; ++mt)
#pragma unroll
      for (int kh = 0; kh < 2; ++kh)
        bf[mt][kh] = *(const f16x8*)&Bs[32 * w + 16 * mt + lc][32 * kh + 8 * lg];
#pragma unroll
    for (int ct = 0; ct < 4; ++ct)
#pragma unroll
      for (int mt = 0; mt < 2; ++mt)
#pragma unroll
        for (int kh = 0; kh < 2; ++kh)
          acc[ct][mt] = __builtin_amdgcn_mfma_f32_16x16x32_f16(a[ct][kh], bf[mt][kh], acc[ct][mt], 0, 0, 0);
    __syncthreads();
  }

#pragma unroll
  for (int ct = 0; ct < 4; ++ct)
#pragma unroll
    for (int r = 0; r < 4; ++r) {
      const int c = c0 + 16 * ct + 4 * lg + r;
      const float bias = b_out[c];
#pragma unroll
      for (int mt = 0; mt < 2; ++mt) {
        const int n = (m0 + 32 * w + 16 * mt + lc) & 2047;
        const size_t off = ((size_t)b * C_IN + c) * N_TOK + n;
        out[off] = x[off] + bias + acc[ct][mt][r];
      }
    }
}

// ---------------- launch ----------------
extern "C" void kernel_launch(void* const* d_in, const int* in_sizes, int n_in,
                              void* d_out, int out_size, void* d_ws, size_t ws_size,
                              hipStream_t stream) {
  const float* x     = (const float*)d_in[0];
  const float* w_qkv = (const float*)d_in[1];
  const float* w_out = (const float*)d_in[2];
  const float* b_out = (const float*)d_in[3];
  float* out = (float*)d_out;

  char* ws = (char*)d_ws;
  unsigned short* xh    = (unsigned short*)(ws);             // 3,145,728 B
  unsigned short* wqh   = (unsigned short*)(ws + 3145728);   //   884,736 B
  unsigned short* woh   = (unsigned short*)(ws + 4030464);   //   294,912 B
  unsigned short* Qb    = (unsigned short*)(ws + 4325376);   // 3,145,728 B
  unsigned short* Kb    = (unsigned short*)(ws + 7471104);   // 3,145,728 B
  unsigned short* Vb    = (unsigned short*)(ws + 10616832);  // 3,145,728 B
  unsigned short* AOh   = (unsigned short*)(ws + 13762560);  // 3,145,728 B
  unsigned short* Opart = (unsigned short*)(ws + 16908288);  // 6,291,456 B
  float2*         mlb   = (float2*)(ws + 23199744);          //   524,288 B

  tr_kernel<<<dim3(32, 6, 4), 256, 0, stream>>>(x, w_qkv, w_out, xh, wqh, woh);
  qkv_mfma<<<dim3(32, 18), 256, 0, stream>>>(xh, wqh, Qb, Kb, Vb);
  attn_kernel<<<dim3(16, 16, 2), 512, 0, stream>>>(Qb, Kb, Vb, Opart, mlb);
  combine_kernel<<<dim3(768), 256, 0, stream>>>(Opart, mlb, AOh);
  proj_mfma<<<dim3(6, 32), 256, 0, stream>>>(AOh, woh, b_out, x, out);
}